// Round 4
// baseline (826.434 us; speedup 1.0000x reference)
//
#include <hip/hip_runtime.h>
#include <stdint.h>

#define QN 512
#define DN 1024
#define BN 64
#define LN 1024

typedef _Float16 f16x8 __attribute__((ext_vector_type(8)));
typedef _Float16 f16x4 __attribute__((ext_vector_type(4)));
typedef float f32x4 __attribute__((ext_vector_type(4)));

// async global->LDS DMA, 16B per lane, lane-linear LDS placement
#define DMA16(gp, lp)                                                        \
  __builtin_amdgcn_global_load_lds(                                          \
      (const __attribute__((address_space(1))) uint32_t*)(const void*)(gp),  \
      (__attribute__((address_space(3))) uint32_t*)(void*)(lp), 16, 0, 0)

// ---------------- kernel 0: zero pace-coupling counters (re-zeroed every launch)
__global__ __launch_bounds__(256) void k_zero(int* __restrict__ cnt) {
  const int i = blockIdx.x * 256 + threadIdx.x;
  if (i < 4096) cnt[i] = 0;
}

// ---------------- kernel 1a: tokens fp32 -> f16 natural [b][l][d] + transposed [b][d][l]
__global__ __launch_bounds__(256) void k_convert(const float* __restrict__ tok,
                                                 _Float16* __restrict__ T,
                                                 _Float16* __restrict__ TT) {
  __shared__ __align__(16) _Float16 tile[64][68];
  const int b = blockIdx.z;
  const int l0 = blockIdx.y * 64, d0 = blockIdx.x * 64;
  const int tid = threadIdx.x;
  const int rr = tid >> 4;
  const int cq = tid & 15;
  const size_t base = (size_t)b * LN * DN;
#pragma unroll
  for (int p = 0; p < 4; ++p) {
    const int l = p * 16 + rr;
    const float4 v = *(const float4*)(tok + base + (size_t)(l0 + l) * DN + d0 + cq * 4);
    f16x4 hv;
    hv[0] = (_Float16)v.x; hv[1] = (_Float16)v.y; hv[2] = (_Float16)v.z; hv[3] = (_Float16)v.w;
    *(f16x4*)(T + base + (size_t)(l0 + l) * DN + d0 + cq * 4) = hv;
    tile[cq * 4 + 0][l] = hv[0];
    tile[cq * 4 + 1][l] = hv[1];
    tile[cq * 4 + 2][l] = hv[2];
    tile[cq * 4 + 3][l] = hv[3];
  }
  __syncthreads();
  const size_t baseT = (size_t)b * DN * LN;
#pragma unroll
  for (int p = 0; p < 4; ++p) {
    const int d = p * 16 + rr;
    const f16x4 hv = *(const f16x4*)(&tile[d][cq * 4]);
    *(f16x4*)(TT + baseT + (size_t)(d0 + d) * LN + l0 + cq * 4) = hv;
  }
}

// ---------------- kernel 1b: queries fp32 -> f16 + 1/max(||q||,eps)
__global__ __launch_bounds__(256) void k_queries(const float* __restrict__ q,
                                                 _Float16* __restrict__ Qh,
                                                 float* __restrict__ invqn) {
  const int qr = blockIdx.x;
  const int tid = threadIdx.x;
  const float4 v = *(const float4*)(q + (size_t)qr * DN + tid * 4);
  float ss = v.x * v.x + v.y * v.y + v.z * v.z + v.w * v.w;
#pragma unroll
  for (int off = 1; off < 64; off <<= 1) ss += __shfl_xor(ss, off, 64);
  __shared__ float red[4];
  if ((tid & 63) == 0) red[tid >> 6] = ss;
  __syncthreads();
  const float tot = red[0] + red[1] + red[2] + red[3];
  f16x4 hv;
  hv[0] = (_Float16)v.x; hv[1] = (_Float16)v.y; hv[2] = (_Float16)v.z; hv[3] = (_Float16)v.w;
  *(f16x4*)(Qh + (size_t)qr * DN + tid * 4) = hv;
  if (tid == 0) invqn[qr] = 1.0f / fmaxf(sqrtf(tot), 1e-12f);
}

// XCD-locality decode: all 8 q-tile blocks of a given b -> same XCD.
__device__ __forceinline__ void decode_bq(int g, int& b, int& q0) {
  const int xcd = g & 7;
  const int t = g >> 3;
  const int qt8 = t & 7;
  b = ((t >> 3) << 3) | xcd;
  q0 = qt8 * 64;
}

// Inter-block pace coupling (perf hint only; hang-safe via bounded spin).
// The 8 q-blocks of a b read BYTE-IDENTICAL slab streams (wave w of block j
// == wave w of block j'). L2 residency for this streaming traffic is ~5 us;
// uncoupled blocks drift past it and every block re-pulls the slab from
// L3/HBM (8x amplification -> the measured ~6 TB/s saturation). At k-steps
// 8/16/24 each wave: drains (its own prefetch only), bumps cnt[b][w][s/8]
// (agent scope = XCD-L2 coherence point), spins <=320 polls for all 8
// siblings, then proceeds REGARDLESS (no dispatch-order dependence, G16-ok).
// Placed only at drained points so counted-vmcnt arithmetic is untouched.
__device__ __forceinline__ void pace_couple(int* __restrict__ cnt, int b, int w, int s,
                                            int lane) {
  int* cp = cnt + (b * 8 + w) * 4 + (s >> 3);
  if (lane == 0) __hip_atomic_fetch_add(cp, 1, __ATOMIC_RELAXED, __HIP_MEMORY_SCOPE_AGENT);
  for (int p = 0; p < 320; ++p) {
    if (__hip_atomic_load(cp, __ATOMIC_RELAXED, __HIP_MEMORY_SCOPE_AGENT) >= 8) break;
    asm volatile("" ::: "memory");
  }
}

// ---------------- kernel 2: scores + exact softmax + num + P (normalized attn, f16)
// r8 = r6 barrier-free counted-vmcnt pipeline + inter-block pace coupling.
__global__ __launch_bounds__(512, 2) void k_scores(const _Float16* __restrict__ Qh,
                                                   const _Float16* __restrict__ T,
                                                   _Float16* __restrict__ P,
                                                   float* __restrict__ numv,
                                                   int* __restrict__ cnt) {
  __shared__ __align__(16) _Float16 Bb[2][32768];  // 2 x 64KB, 16B-swizzled, wave-private slices
  __shared__ float maxbuf[8][64];
  __shared__ float sumbuf[8][64];
  __shared__ float numbuf[8][64];
  __shared__ float Mbuf[64];
  __shared__ float Rbuf[64];
  int b, q0;
  decode_bq(blockIdx.x, b, q0);
  const int tid = threadIdx.x;
  const int w = tid >> 6, lane = tid & 63, c = lane & 15, quad = lane >> 4;

  const char* __restrict__ gT = (const char*)(T + (size_t)b * LN * DN);
  const _Float16* __restrict__ gA = Qh + (size_t)q0 * DN;

  // per-lane DMA source (inverse of the LDS swizzle): slot = slab*64 + lane
  const int r4 = lane >> 2;                              // row within 16-row slab
  const int qsw = ((lane & 3) - ((lane >> 3) & 3)) & 3;  // source 16B colgroup
  const char* gBbase = gT + (size_t)(w * 128 + r4) * 2048 + qsw * 16;

  // fragment LDS offsets (f16 units): row*32 + swizzled-colgroup*8
  const int bswz = ((quad + ((c >> 1) & 3)) & 3) * 8;
  const int boff = (w * 128 + c) * 32 + bswz;  // + lt*512

  f32x4 acc[4][8];
#pragma unroll
  for (int i = 0; i < 4; ++i)
#pragma unroll
    for (int j = 0; j < 8; ++j) acc[i][j] = 0.f;

  // A base per lane (f16 elems): row qt*16+c, colgroup quad
  const _Float16* gAl = gA + (size_t)c * DN + quad * 8;

  // prologue: A(0) -> regs, B(0) -> LDS buf0. No drain; iter 0's wait handles it.
  f16x8 a_cur[4], a_nxt[4];
#pragma unroll
  for (int qt = 0; qt < 4; ++qt) a_cur[qt] = *(const f16x8*)(gAl + (size_t)qt * 16 * DN);
#pragma unroll
  for (int j = 0; j < 8; ++j) DMA16(gBbase + (size_t)j * 32768, &Bb[0][(w * 8 + j) * 512]);

  for (int s = 0; s < 31; ++s) {
    if ((s & 7) == 0 && s != 0) {
      // coupling point: drain own prefetch (still valid in LDS), sync pace
      asm volatile("s_waitcnt vmcnt(0)" ::: "memory");
      __builtin_amdgcn_sched_barrier(0);
      pace_couple(cnt, b, w, s, lane);
      __builtin_amdgcn_sched_barrier(0);
    }
    const int cur = s & 1;
    const int sn = s + 1;
    // issue A(s+1) -> regs
#pragma unroll
    for (int qt = 0; qt < 4; ++qt)
      a_nxt[qt] = *(const f16x8*)(gAl + (size_t)qt * 16 * DN + sn * 32);
    // WAR fence: this wave's ds_reads on buf[cur^1] (iter s-1) drained before overwrite.
    asm volatile("s_waitcnt lgkmcnt(0)" ::: "memory");
    // issue B(s+1) -> LDS buf[cur^1] (wave-private region)
#pragma unroll
    for (int j = 0; j < 8; ++j)
      DMA16(gBbase + (size_t)j * 32768 + sn * 64, &Bb[cur ^ 1][(w * 8 + j) * 512]);
    // counted wait: allow A(s+1)+B(s+1)=12 in flight; forces A(s),B(s) landed
    asm volatile("s_waitcnt vmcnt(12)" ::: "memory");
    __builtin_amdgcn_sched_barrier(0);

    const _Float16* __restrict__ Bp = &Bb[cur][0];
#pragma unroll
    for (int lt = 0; lt < 8; ++lt) {
      const f16x8 bv = *(const f16x8*)(Bp + boff + lt * 512);
#pragma unroll
      for (int qt = 0; qt < 4; ++qt)
        acc[qt][lt] = __builtin_amdgcn_mfma_f32_16x16x32_f16(a_cur[qt], bv, acc[qt][lt], 0, 0, 0);
    }
#pragma unroll
    for (int qt = 0; qt < 4; ++qt) a_cur[qt] = a_nxt[qt];
  }
  // peeled final step (s=31, buffer 1): drain everything, compute, no issue
  asm volatile("s_waitcnt vmcnt(0)" ::: "memory");
  __builtin_amdgcn_sched_barrier(0);
  {
    const _Float16* __restrict__ Bp = &Bb[1][0];
#pragma unroll
    for (int lt = 0; lt < 8; ++lt) {
      const f16x8 bv = *(const f16x8*)(Bp + boff + lt * 512);
#pragma unroll
      for (int qt = 0; qt < 4; ++qt)
        acc[qt][lt] = __builtin_amdgcn_mfma_f32_16x16x32_f16(a_cur[qt], bv, acc[qt][lt], 0, 0, 0);
    }
  }

  // acc[qt][lt][r] = u  at row q = qt*16+quad*4+r , col l = w*128+lt*16+c
  float mx[4][4];
#pragma unroll
  for (int qt = 0; qt < 4; ++qt)
#pragma unroll
    for (int r = 0; r < 4; ++r) {
      float m = acc[qt][0][r];
#pragma unroll
      for (int lt = 1; lt < 8; ++lt) m = fmaxf(m, acc[qt][lt][r]);
      mx[qt][r] = m;
    }
#pragma unroll
  for (int off = 1; off < 16; off <<= 1)
#pragma unroll
    for (int qt = 0; qt < 4; ++qt)
#pragma unroll
      for (int r = 0; r < 4; ++r) mx[qt][r] = fmaxf(mx[qt][r], __shfl_xor(mx[qt][r], off, 64));
  if (c == 0)
#pragma unroll
    for (int qt = 0; qt < 4; ++qt)
#pragma unroll
      for (int r = 0; r < 4; ++r) maxbuf[w][qt * 16 + quad * 4 + r] = mx[qt][r];
  __syncthreads();
  if (tid < 64) {
    float m = maxbuf[0][tid];
#pragma unroll
    for (int ww = 1; ww < 8; ++ww) m = fmaxf(m, maxbuf[ww][tid]);
    Mbuf[tid] = m;
  }
  __syncthreads();

  const float KE = 0.045084220027780106f;  // log2(e)/32  (scores = u/sqrt(1024))
  float Mr[4][4], sl[4][4], nl[4][4];
#pragma unroll
  for (int qt = 0; qt < 4; ++qt)
#pragma unroll
    for (int r = 0; r < 4; ++r) {
      Mr[qt][r] = Mbuf[qt * 16 + quad * 4 + r];
      sl[qt][r] = 0.f;
      nl[qt][r] = 0.f;
    }
#pragma unroll
  for (int qt = 0; qt < 4; ++qt)
#pragma unroll
    for (int lt = 0; lt < 8; ++lt)
#pragma unroll
      for (int r = 0; r < 4; ++r) {
        const float u = acc[qt][lt][r];
        const float p = exp2f((u - Mr[qt][r]) * KE);
        acc[qt][lt][r] = p;
        sl[qt][r] += p;
        nl[qt][r] += p * u;
      }
#pragma unroll
  for (int off = 1; off < 16; off <<= 1)
#pragma unroll
    for (int qt = 0; qt < 4; ++qt)
#pragma unroll
      for (int r = 0; r < 4; ++r) {
        sl[qt][r] += __shfl_xor(sl[qt][r], off, 64);
        nl[qt][r] += __shfl_xor(nl[qt][r], off, 64);
      }
  if (c == 0)
#pragma unroll
    for (int qt = 0; qt < 4; ++qt)
#pragma unroll
      for (int r = 0; r < 4; ++r) {
        sumbuf[w][qt * 16 + quad * 4 + r] = sl[qt][r];
        numbuf[w][qt * 16 + quad * 4 + r] = nl[qt][r];
      }
  __syncthreads();
  if (tid < 64) {
    float S = 0.f, N = 0.f;
#pragma unroll
    for (int ww = 0; ww < 8; ++ww) {
      S += sumbuf[ww][tid];
      N += numbuf[ww][tid];
    }
    Rbuf[tid] = 1.0f / S;
    numv[(size_t)b * QN + q0 + tid] = N / S;  // = q . agg  (exact fp32 ratio)
  }
  __syncthreads();

  _Float16* Pb = P + ((size_t)b * QN + q0) * LN;
#pragma unroll
  for (int qt = 0; qt < 4; ++qt)
#pragma unroll
    for (int r = 0; r < 4; ++r) {
      const int row = qt * 16 + quad * 4 + r;
      const float rS = Rbuf[row];
      _Float16* prow = Pb + (size_t)row * LN + c;
#pragma unroll
      for (int lt = 0; lt < 8; ++lt) prow[w * 128 + lt * 16] = (_Float16)(acc[qt][lt][r] * rS);
    }
}

// ---------------- kernel 3: agg = P @ T (via TT), reduce to ||agg||^2 per (b,q)
// same barrier-free pipeline + pace coupling; B rows = d (from TT), A rows = q (from P)
__global__ __launch_bounds__(512, 2) void k_agg(const _Float16* __restrict__ P,
                                                const _Float16* __restrict__ TT,
                                                float* __restrict__ norm2,
                                                int* __restrict__ cnt) {
  __shared__ __align__(16) _Float16 Bb[2][32768];
  __shared__ float redbuf[8][64];
  int b, q0;
  decode_bq(blockIdx.x, b, q0);
  const int tid = threadIdx.x;
  const int w = tid >> 6, lane = tid & 63, c = lane & 15, quad = lane >> 4;

  const char* __restrict__ gT = (const char*)(TT + (size_t)b * DN * LN);
  const _Float16* __restrict__ gA = P + ((size_t)b * QN + q0) * LN;

  const int r4 = lane >> 2;
  const int qsw = ((lane & 3) - ((lane >> 3) & 3)) & 3;
  const char* gBbase = gT + (size_t)(w * 128 + r4) * 2048 + qsw * 16;

  const int bswz = ((quad + ((c >> 1) & 3)) & 3) * 8;
  const int boff = (w * 128 + c) * 32 + bswz;

  f32x4 acc[4][8];
#pragma unroll
  for (int i = 0; i < 4; ++i)
#pragma unroll
    for (int j = 0; j < 8; ++j) acc[i][j] = 0.f;

  const _Float16* gAl = gA + (size_t)c * LN + quad * 8;

  f16x8 a_cur[4], a_nxt[4];
#pragma unroll
  for (int qt = 0; qt < 4; ++qt) a_cur[qt] = *(const f16x8*)(gAl + (size_t)qt * 16 * LN);
#pragma unroll
  for (int j = 0; j < 8; ++j) DMA16(gBbase + (size_t)j * 32768, &Bb[0][(w * 8 + j) * 512]);

  for (int s = 0; s < 31; ++s) {
    if ((s & 7) == 0 && s != 0) {
      asm volatile("s_waitcnt vmcnt(0)" ::: "memory");
      __builtin_amdgcn_sched_barrier(0);
      pace_couple(cnt, b, w, s, lane);
      __builtin_amdgcn_sched_barrier(0);
    }
    const int cur = s & 1;
    const int sn = s + 1;
#pragma unroll
    for (int qt = 0; qt < 4; ++qt)
      a_nxt[qt] = *(const f16x8*)(gAl + (size_t)qt * 16 * LN + sn * 32);
    asm volatile("s_waitcnt lgkmcnt(0)" ::: "memory");
#pragma unroll
    for (int j = 0; j < 8; ++j)
      DMA16(gBbase + (size_t)j * 32768 + sn * 64, &Bb[cur ^ 1][(w * 8 + j) * 512]);
    asm volatile("s_waitcnt vmcnt(12)" ::: "memory");
    __builtin_amdgcn_sched_barrier(0);

    const _Float16* __restrict__ Bp = &Bb[cur][0];
#pragma unroll
    for (int dt = 0; dt < 8; ++dt) {
      const f16x8 bv = *(const f16x8*)(Bp + boff + dt * 512);
#pragma unroll
      for (int qt = 0; qt < 4; ++qt)
        acc[qt][dt] = __builtin_amdgcn_mfma_f32_16x16x32_f16(a_cur[qt], bv, acc[qt][dt], 0, 0, 0);
    }
#pragma unroll
    for (int qt = 0; qt < 4; ++qt) a_cur[qt] = a_nxt[qt];
  }
  asm volatile("s_waitcnt vmcnt(0)" ::: "memory");
  __builtin_amdgcn_sched_barrier(0);
  {
    const _Float16* __restrict__ Bp = &Bb[1][0];
#pragma unroll
    for (int dt = 0; dt < 8; ++dt) {
      const f16x8 bv = *(const f16x8*)(Bp + boff + dt * 512);
#pragma unroll
      for (int qt = 0; qt < 4; ++qt)
        acc[qt][dt] = __builtin_amdgcn_mfma_f32_16x16x32_f16(a_cur[qt], bv, acc[qt][dt], 0, 0, 0);
    }
  }

  float ss[4][4];
#pragma unroll
  for (int qt = 0; qt < 4; ++qt)
#pragma unroll
    for (int r = 0; r < 4; ++r) {
      float s = 0.f;
#pragma unroll
      for (int dt = 0; dt < 8; ++dt) {
        const float v = acc[qt][dt][r];
        s += v * v;
      }
      ss[qt][r] = s;
    }
#pragma unroll
  for (int off = 1; off < 16; off <<= 1)
#pragma unroll
    for (int qt = 0; qt < 4; ++qt)
#pragma unroll
      for (int r = 0; r < 4; ++r) ss[qt][r] += __shfl_xor(ss[qt][r], off, 64);
  if (c == 0)
#pragma unroll
    for (int qt = 0; qt < 4; ++qt)
#pragma unroll
      for (int r = 0; r < 4; ++r) redbuf[w][qt * 16 + quad * 4 + r] = ss[qt][r];
  __syncthreads();
  if (tid < 64) {
    float s = 0.f;
#pragma unroll
    for (int ww = 0; ww < 8; ++ww) s += redbuf[ww][tid];
    norm2[(size_t)b * QN + q0 + tid] = s;
  }
}

// ---------------- kernel 4: logits[q][b] = num * invqn / max(||agg||, eps)
__global__ __launch_bounds__(256) void k_final(const float* __restrict__ numv,
                                               const float* __restrict__ norm2,
                                               const float* __restrict__ invqn,
                                               float* __restrict__ out) {
  const int idx = blockIdx.x * 256 + threadIdx.x;  // 0..32767
  const int q = idx >> 6, b = idx & 63;
  const float n = numv[(size_t)b * QN + q];
  const float d = sqrtf(norm2[(size_t)b * QN + q]);
  out[idx] = n * invqn[q] / fmaxf(d, 1e-12f);
}

extern "C" void kernel_launch(void* const* d_in, const int* in_sizes, int n_in,
                              void* d_out, int out_size, void* d_ws, size_t ws_size,
                              hipStream_t stream) {
  (void)in_sizes; (void)n_in; (void)out_size; (void)ws_size;
  const float* queries = (const float*)d_in[0];
  const float* tok = (const float*)d_in[1];
  float* out = (float*)d_out;
  char* ws = (char*)d_ws;

  // workspace layout (bytes)
  _Float16* TT = (_Float16*)(ws + 0);           // 128 MB  [b][d][l]
  _Float16* T = (_Float16*)(ws + 134217728);    // 128 MB  [b][l][d]
  _Float16* P = (_Float16*)(ws + 268435456);    // 64 MB   [b][q][l]
  _Float16* Qh = (_Float16*)(ws + 335544320);   // 1 MB    [q][d]
  float* invqn = (float*)(ws + 336592896);      // 2 KB
  float* numv = (float*)(ws + 336594944);       // 128 KB  [b][q]
  float* norm2 = (float*)(ws + 336726016);      // 128 KB  [b][q]
  int* cnt = (int*)(ws + 336857088);            // 16 KB: [2][64][8][4] pace counters

  hipLaunchKernelGGL(k_zero, dim3(16), dim3(256), 0, stream, cnt);
  hipLaunchKernelGGL(k_convert, dim3(16, 16, 64), dim3(256), 0, stream, tok, T, TT);
  hipLaunchKernelGGL(k_queries, dim3(512), dim3(256), 0, stream, queries, Qh, invqn);
  hipLaunchKernelGGL(k_scores, dim3(512), dim3(512), 0, stream, Qh, T, P, numv, cnt);
  hipLaunchKernelGGL(k_agg, dim3(512), dim3(512), 0, stream, P, TT, norm2, cnt + 2048);
  hipLaunchKernelGGL(k_final, dim3(128), dim3(256), 0, stream, numv, norm2, invqn, out);
}

// Round 5
// 650.104 us; speedup vs baseline: 1.2712x; 1.2712x over previous
//
#include <hip/hip_runtime.h>
#include <stdint.h>

#define QN 512
#define DN 1024
#define BN 64
#define LN 1024

typedef _Float16 f16x8 __attribute__((ext_vector_type(8)));
typedef _Float16 f16x4 __attribute__((ext_vector_type(4)));
typedef float f32x4 __attribute__((ext_vector_type(4)));

// async global->LDS DMA, 16B per lane, lane-linear LDS placement
#define DMA16(gp, lp)                                                        \
  __builtin_amdgcn_global_load_lds(                                          \
      (const __attribute__((address_space(1))) uint32_t*)(const void*)(gp),  \
      (__attribute__((address_space(3))) uint32_t*)(void*)(lp), 16, 0, 0)

// ---------------- kernel 1a: tokens fp32 -> staged DMA images
// T2[b][s][off]  : step-s (d-chunk 32) LDS image for k_scores (rows=l, k=d)
// TT2[b][s2][off]: step-s2 (l-chunk 32) LDS image for k_agg   (rows=d, k=l)
// Image layout (64 KB = 64 slabs x 1 KB), for (row R, kk in [0,32)):
//   slab=R>>4, r4=R&15, g=kk>>3, e=kk&7, m=(g+((r4>>1)&3))&3,
//   off = slab*512 + (r4*4+m)*8 + e     (f16 units)
// This bakes the 16B-unit XOR swizzle into global memory so the k-loop DMA
// is perfectly contiguous (1024 B per instruction, 8 full lines).
__global__ __launch_bounds__(256) void k_convert(const float* __restrict__ tok,
                                                 _Float16* __restrict__ T2,
                                                 _Float16* __restrict__ TT2) {
  __shared__ __align__(16) _Float16 tile[64][68];
  const int b = blockIdx.z;
  const int l0 = blockIdx.y * 64, d0 = blockIdx.x * 64;
  const int tid = threadIdx.x;
  const int rr = tid >> 4;
  const int cq = tid & 15;
  const int g = (cq >> 1) & 3;     // 16B group within 32-k chunk
  const int e0 = (cq & 1) * 4;     // f16 offset within 16B slot
  const int sq = cq >> 3;          // image index offset
  const size_t base = (size_t)b * LN * DN;
  const size_t ib = (size_t)b * 1048576;  // 1M f16 per b per array
#pragma unroll
  for (int p = 0; p < 4; ++p) {
    const int l = l0 + p * 16 + rr;
    const float4 v = *(const float4*)(tok + base + (size_t)l * DN + d0 + cq * 4);
    f16x4 hv;
    hv[0] = (_Float16)v.x; hv[1] = (_Float16)v.y; hv[2] = (_Float16)v.z; hv[3] = (_Float16)v.w;
    // T2: R=l, d-chunk s
    const int s = (d0 >> 5) + sq;
    const int slab = l >> 4, r4 = l & 15;
    const int m = (g + ((r4 >> 1) & 3)) & 3;
    const int off = slab * 512 + (r4 * 4 + m) * 8 + e0;
    *(f16x4*)(T2 + ib + (size_t)s * 32768 + off) = hv;
    const int ll = p * 16 + rr;
    tile[cq * 4 + 0][ll] = hv[0];
    tile[cq * 4 + 1][ll] = hv[1];
    tile[cq * 4 + 2][ll] = hv[2];
    tile[cq * 4 + 3][ll] = hv[3];
  }
  __syncthreads();
#pragma unroll
  for (int p = 0; p < 4; ++p) {
    const int dl = p * 16 + rr;
    const int d = d0 + dl;
    const f16x4 hv = *(const f16x4*)(&tile[dl][cq * 4]);
    // TT2: R=d, l-chunk s2
    const int s2 = (l0 >> 5) + sq;
    const int slab = d >> 4, r4 = d & 15;
    const int m = (g + ((r4 >> 1) & 3)) & 3;
    const int off = slab * 512 + (r4 * 4 + m) * 8 + e0;
    *(f16x4*)(TT2 + ib + (size_t)s2 * 32768 + off) = hv;
  }
}

// ---------------- kernel 1b: queries fp32 -> f16 + 1/max(||q||,eps)
__global__ __launch_bounds__(256) void k_queries(const float* __restrict__ q,
                                                 _Float16* __restrict__ Qh,
                                                 float* __restrict__ invqn) {
  const int qr = blockIdx.x;
  const int tid = threadIdx.x;
  const float4 v = *(const float4*)(q + (size_t)qr * DN + tid * 4);
  float ss = v.x * v.x + v.y * v.y + v.z * v.z + v.w * v.w;
#pragma unroll
  for (int off = 1; off < 64; off <<= 1) ss += __shfl_xor(ss, off, 64);
  __shared__ float red[4];
  if ((tid & 63) == 0) red[tid >> 6] = ss;
  __syncthreads();
  const float tot = red[0] + red[1] + red[2] + red[3];
  f16x4 hv;
  hv[0] = (_Float16)v.x; hv[1] = (_Float16)v.y; hv[2] = (_Float16)v.z; hv[3] = (_Float16)v.w;
  *(f16x4*)(Qh + (size_t)qr * DN + tid * 4) = hv;
  if (tid == 0) invqn[qr] = 1.0f / fmaxf(sqrtf(tot), 1e-12f);
}

// XCD-locality decode: all 8 q-tile blocks of a given b -> same XCD.
__device__ __forceinline__ void decode_bq(int g, int& b, int& q0) {
  const int xcd = g & 7;
  const int t = g >> 3;
  const int qt8 = t & 7;
  b = ((t >> 3) << 3) | xcd;
  q0 = qt8 * 64;
}

// ---------------- kernel 2: scores + exact softmax + num + P (normalized attn, f16)
// r9 = r6 barrier-free counted-vmcnt pipeline, but B staged from the
// pre-swizzled contiguous images (T2): every DMA16 moves 1024 B contiguous
// (8 full cache lines) instead of 16 half-used lines. ds_read side and the
// vmcnt protocol are byte-identical to r6 (verified element-level equivalence
// of the image math). Pace-coupling (r8) removed — it regressed.
__global__ __launch_bounds__(512, 2) void k_scores(const _Float16* __restrict__ Qh,
                                                   const _Float16* __restrict__ T2,
                                                   _Float16* __restrict__ P,
                                                   float* __restrict__ numv) {
  __shared__ __align__(16) _Float16 Bb[2][32768];  // 2 x 64KB step images
  __shared__ float maxbuf[8][64];
  __shared__ float sumbuf[8][64];
  __shared__ float numbuf[8][64];
  __shared__ float Mbuf[64];
  __shared__ float Rbuf[64];
  int b, q0;
  decode_bq(blockIdx.x, b, q0);
  const int tid = threadIdx.x;
  const int w = tid >> 6, lane = tid & 63, c = lane & 15, quad = lane >> 4;

  // contiguous per-lane DMA source into the step image
  const char* __restrict__ gB = (const char*)(T2 + (size_t)b * 1048576) + lane * 16;
  const _Float16* __restrict__ gA = Qh + (size_t)q0 * DN;

  // fragment LDS offsets (f16 units): row*32 + swizzled-colgroup*8
  const int bswz = ((quad + ((c >> 1) & 3)) & 3) * 8;
  const int boff = (w * 128 + c) * 32 + bswz;  // + lt*512

  f32x4 acc[4][8];
#pragma unroll
  for (int i = 0; i < 4; ++i)
#pragma unroll
    for (int j = 0; j < 8; ++j) acc[i][j] = 0.f;

  // A base per lane (f16 elems): row qt*16+c, colgroup quad
  const _Float16* gAl = gA + (size_t)c * DN + quad * 8;

  // prologue: A(0) -> regs, B(0) -> LDS buf0. No drain; iter 0's wait handles it.
  f16x8 a_cur[4], a_nxt[4];
#pragma unroll
  for (int qt = 0; qt < 4; ++qt) a_cur[qt] = *(const f16x8*)(gAl + (size_t)qt * 16 * DN);
#pragma unroll
  for (int j = 0; j < 8; ++j)
    DMA16(gB + (size_t)(w * 8 + j) * 1024, &Bb[0][(w * 8 + j) * 512]);

  for (int s = 0; s < 31; ++s) {
    const int cur = s & 1;
    const int sn = s + 1;
    // issue A(s+1) -> regs
#pragma unroll
    for (int qt = 0; qt < 4; ++qt)
      a_nxt[qt] = *(const f16x8*)(gAl + (size_t)qt * 16 * DN + sn * 32);
    // WAR fence: this wave's ds_reads on buf[cur^1] (iter s-1) drained before overwrite.
    asm volatile("s_waitcnt lgkmcnt(0)" ::: "memory");
    // issue B(s+1) -> LDS buf[cur^1] (wave-private region), contiguous stream
#pragma unroll
    for (int j = 0; j < 8; ++j)
      DMA16(gB + (size_t)sn * 65536 + (size_t)(w * 8 + j) * 1024, &Bb[cur ^ 1][(w * 8 + j) * 512]);
    // counted wait: allow A(s+1)+B(s+1)=12 in flight; forces A(s),B(s) landed
    asm volatile("s_waitcnt vmcnt(12)" ::: "memory");
    __builtin_amdgcn_sched_barrier(0);

    const _Float16* __restrict__ Bp = &Bb[cur][0];
#pragma unroll
    for (int lt = 0; lt < 8; ++lt) {
      const f16x8 bv = *(const f16x8*)(Bp + boff + lt * 512);
#pragma unroll
      for (int qt = 0; qt < 4; ++qt)
        acc[qt][lt] = __builtin_amdgcn_mfma_f32_16x16x32_f16(a_cur[qt], bv, acc[qt][lt], 0, 0, 0);
    }
#pragma unroll
    for (int qt = 0; qt < 4; ++qt) a_cur[qt] = a_nxt[qt];
  }
  // peeled final step (s=31, buffer 1): drain everything, compute, no issue
  asm volatile("s_waitcnt vmcnt(0)" ::: "memory");
  __builtin_amdgcn_sched_barrier(0);
  {
    const _Float16* __restrict__ Bp = &Bb[1][0];
#pragma unroll
    for (int lt = 0; lt < 8; ++lt) {
      const f16x8 bv = *(const f16x8*)(Bp + boff + lt * 512);
#pragma unroll
      for (int qt = 0; qt < 4; ++qt)
        acc[qt][lt] = __builtin_amdgcn_mfma_f32_16x16x32_f16(a_cur[qt], bv, acc[qt][lt], 0, 0, 0);
    }
  }

  // acc[qt][lt][r] = u  at row q = qt*16+quad*4+r , col l = w*128+lt*16+c
  float mx[4][4];
#pragma unroll
  for (int qt = 0; qt < 4; ++qt)
#pragma unroll
    for (int r = 0; r < 4; ++r) {
      float m = acc[qt][0][r];
#pragma unroll
      for (int lt = 1; lt < 8; ++lt) m = fmaxf(m, acc[qt][lt][r]);
      mx[qt][r] = m;
    }
#pragma unroll
  for (int off = 1; off < 16; off <<= 1)
#pragma unroll
    for (int qt = 0; qt < 4; ++qt)
#pragma unroll
      for (int r = 0; r < 4; ++r) mx[qt][r] = fmaxf(mx[qt][r], __shfl_xor(mx[qt][r], off, 64));
  if (c == 0)
#pragma unroll
    for (int qt = 0; qt < 4; ++qt)
#pragma unroll
      for (int r = 0; r < 4; ++r) maxbuf[w][qt * 16 + quad * 4 + r] = mx[qt][r];
  __syncthreads();
  if (tid < 64) {
    float m = maxbuf[0][tid];
#pragma unroll
    for (int ww = 1; ww < 8; ++ww) m = fmaxf(m, maxbuf[ww][tid]);
    Mbuf[tid] = m;
  }
  __syncthreads();

  const float KE = 0.045084220027780106f;  // log2(e)/32  (scores = u/sqrt(1024))
  float Mr[4][4], sl[4][4], nl[4][4];
#pragma unroll
  for (int qt = 0; qt < 4; ++qt)
#pragma unroll
    for (int r = 0; r < 4; ++r) {
      Mr[qt][r] = Mbuf[qt * 16 + quad * 4 + r];
      sl[qt][r] = 0.f;
      nl[qt][r] = 0.f;
    }
#pragma unroll
  for (int qt = 0; qt < 4; ++qt)
#pragma unroll
    for (int lt = 0; lt < 8; ++lt)
#pragma unroll
      for (int r = 0; r < 4; ++r) {
        const float u = acc[qt][lt][r];
        const float p = exp2f((u - Mr[qt][r]) * KE);
        acc[qt][lt][r] = p;
        sl[qt][r] += p;
        nl[qt][r] += p * u;
      }
#pragma unroll
  for (int off = 1; off < 16; off <<= 1)
#pragma unroll
    for (int qt = 0; qt < 4; ++qt)
#pragma unroll
      for (int r = 0; r < 4; ++r) {
        sl[qt][r] += __shfl_xor(sl[qt][r], off, 64);
        nl[qt][r] += __shfl_xor(nl[qt][r], off, 64);
      }
  if (c == 0)
#pragma unroll
    for (int qt = 0; qt < 4; ++qt)
#pragma unroll
      for (int r = 0; r < 4; ++r) {
        sumbuf[w][qt * 16 + quad * 4 + r] = sl[qt][r];
        numbuf[w][qt * 16 + quad * 4 + r] = nl[qt][r];
      }
  __syncthreads();
  if (tid < 64) {
    float S = 0.f, N = 0.f;
#pragma unroll
    for (int ww = 0; ww < 8; ++ww) {
      S += sumbuf[ww][tid];
      N += numbuf[ww][tid];
    }
    Rbuf[tid] = 1.0f / S;
    numv[(size_t)b * QN + q0 + tid] = N / S;  // = q . agg  (exact fp32 ratio)
  }
  __syncthreads();

  _Float16* Pb = P + ((size_t)b * QN + q0) * LN;
#pragma unroll
  for (int qt = 0; qt < 4; ++qt)
#pragma unroll
    for (int r = 0; r < 4; ++r) {
      const int row = qt * 16 + quad * 4 + r;
      const float rS = Rbuf[row];
      _Float16* prow = Pb + (size_t)row * LN + c;
#pragma unroll
      for (int lt = 0; lt < 8; ++lt) prow[w * 128 + lt * 16] = (_Float16)(acc[qt][lt][r] * rS);
    }
}

// ---------------- kernel 3: agg = P @ T (via TT2 images), ||agg||^2 per (b,q)
// same pipeline; B = TT2 step images (rows=d, k=l), A = P rows (natural layout)
__global__ __launch_bounds__(512, 2) void k_agg(const _Float16* __restrict__ P,
                                                const _Float16* __restrict__ TT2,
                                                float* __restrict__ norm2) {
  __shared__ __align__(16) _Float16 Bb[2][32768];
  __shared__ float redbuf[8][64];
  int b, q0;
  decode_bq(blockIdx.x, b, q0);
  const int tid = threadIdx.x;
  const int w = tid >> 6, lane = tid & 63, c = lane & 15, quad = lane >> 4;

  const char* __restrict__ gB = (const char*)(TT2 + (size_t)b * 1048576) + lane * 16;
  const _Float16* __restrict__ gA = P + ((size_t)b * QN + q0) * LN;

  const int bswz = ((quad + ((c >> 1) & 3)) & 3) * 8;
  const int boff = (w * 128 + c) * 32 + bswz;

  f32x4 acc[4][8];
#pragma unroll
  for (int i = 0; i < 4; ++i)
#pragma unroll
    for (int j = 0; j < 8; ++j) acc[i][j] = 0.f;

  const _Float16* gAl = gA + (size_t)c * LN + quad * 8;

  f16x8 a_cur[4], a_nxt[4];
#pragma unroll
  for (int qt = 0; qt < 4; ++qt) a_cur[qt] = *(const f16x8*)(gAl + (size_t)qt * 16 * LN);
#pragma unroll
  for (int j = 0; j < 8; ++j)
    DMA16(gB + (size_t)(w * 8 + j) * 1024, &Bb[0][(w * 8 + j) * 512]);

  for (int s = 0; s < 31; ++s) {
    const int cur = s & 1;
    const int sn = s + 1;
#pragma unroll
    for (int qt = 0; qt < 4; ++qt)
      a_nxt[qt] = *(const f16x8*)(gAl + (size_t)qt * 16 * LN + sn * 32);
    asm volatile("s_waitcnt lgkmcnt(0)" ::: "memory");
#pragma unroll
    for (int j = 0; j < 8; ++j)
      DMA16(gB + (size_t)sn * 65536 + (size_t)(w * 8 + j) * 1024, &Bb[cur ^ 1][(w * 8 + j) * 512]);
    asm volatile("s_waitcnt vmcnt(12)" ::: "memory");
    __builtin_amdgcn_sched_barrier(0);

    const _Float16* __restrict__ Bp = &Bb[cur][0];
#pragma unroll
    for (int dt = 0; dt < 8; ++dt) {
      const f16x8 bv = *(const f16x8*)(Bp + boff + dt * 512);
#pragma unroll
      for (int qt = 0; qt < 4; ++qt)
        acc[qt][dt] = __builtin_amdgcn_mfma_f32_16x16x32_f16(a_cur[qt], bv, acc[qt][dt], 0, 0, 0);
    }
#pragma unroll
    for (int qt = 0; qt < 4; ++qt) a_cur[qt] = a_nxt[qt];
  }
  asm volatile("s_waitcnt vmcnt(0)" ::: "memory");
  __builtin_amdgcn_sched_barrier(0);
  {
    const _Float16* __restrict__ Bp = &Bb[1][0];
#pragma unroll
    for (int dt = 0; dt < 8; ++dt) {
      const f16x8 bv = *(const f16x8*)(Bp + boff + dt * 512);
#pragma unroll
      for (int qt = 0; qt < 4; ++qt)
        acc[qt][dt] = __builtin_amdgcn_mfma_f32_16x16x32_f16(a_cur[qt], bv, acc[qt][dt], 0, 0, 0);
    }
  }

  float ss[4][4];
#pragma unroll
  for (int qt = 0; qt < 4; ++qt)
#pragma unroll
    for (int r = 0; r < 4; ++r) {
      float s = 0.f;
#pragma unroll
      for (int dt = 0; dt < 8; ++dt) {
        const float v = acc[qt][dt][r];
        s += v * v;
      }
      ss[qt][r] = s;
    }
#pragma unroll
  for (int off = 1; off < 16; off <<= 1)
#pragma unroll
    for (int qt = 0; qt < 4; ++qt)
#pragma unroll
      for (int r = 0; r < 4; ++r) ss[qt][r] += __shfl_xor(ss[qt][r], off, 64);
  if (c == 0)
#pragma unroll
    for (int qt = 0; qt < 4; ++qt)
#pragma unroll
      for (int r = 0; r < 4; ++r) redbuf[w][qt * 16 + quad * 4 + r] = ss[qt][r];
  __syncthreads();
  if (tid < 64) {
    float s = 0.f;
#pragma unroll
    for (int ww = 0; ww < 8; ++ww) s += redbuf[ww][tid];
    norm2[(size_t)b * QN + q0 + tid] = s;
  }
}

// ---------------- kernel 4: logits[q][b] = num * invqn / max(||agg||, eps)
__global__ __launch_bounds__(256) void k_final(const float* __restrict__ numv,
                                               const float* __restrict__ norm2,
                                               const float* __restrict__ invqn,
                                               float* __restrict__ out) {
  const int idx = blockIdx.x * 256 + threadIdx.x;  // 0..32767
  const int q = idx >> 6, b = idx & 63;
  const float n = numv[(size_t)b * QN + q];
  const float d = sqrtf(norm2[(size_t)b * QN + q]);
  out[idx] = n * invqn[q] / fmaxf(d, 1e-12f);
}

extern "C" void kernel_launch(void* const* d_in, const int* in_sizes, int n_in,
                              void* d_out, int out_size, void* d_ws, size_t ws_size,
                              hipStream_t stream) {
  (void)in_sizes; (void)n_in; (void)out_size; (void)ws_size;
  const float* queries = (const float*)d_in[0];
  const float* tok = (const float*)d_in[1];
  float* out = (float*)d_out;
  char* ws = (char*)d_ws;

  // workspace layout (bytes)
  _Float16* T2 = (_Float16*)(ws + 0);           // 128 MB  staged images for k_scores
  _Float16* TT2 = (_Float16*)(ws + 134217728);  // 128 MB  staged images for k_agg
  _Float16* P = (_Float16*)(ws + 268435456);    // 64 MB   [b][q][l]
  _Float16* Qh = (_Float16*)(ws + 335544320);   // 1 MB    [q][d]
  float* invqn = (float*)(ws + 336592896);      // 2 KB
  float* numv = (float*)(ws + 336594944);       // 128 KB  [b][q]
  float* norm2 = (float*)(ws + 336726016);      // 128 KB  [b][q]

  hipLaunchKernelGGL(k_convert, dim3(16, 16, 64), dim3(256), 0, stream, tok, T2, TT2);
  hipLaunchKernelGGL(k_queries, dim3(512), dim3(256), 0, stream, queries, Qh, invqn);
  hipLaunchKernelGGL(k_scores, dim3(512), dim3(512), 0, stream, Qh, T2, P, numv);
  hipLaunchKernelGGL(k_agg, dim3(512), dim3(512), 0, stream, P, TT2, norm2);
  hipLaunchKernelGGL(k_final, dim3(128), dim3(256), 0, stream, numv, norm2, invqn, out);
}